// Round 16
// baseline (167.631 us; speedup 1.0000x reference)
//
#include <hip/hip_runtime.h>
#include <hip/hip_bf16.h>

#define D_DIM 1024
#define NE 16
#define RK 64
#define NTOK 16384

typedef __bf16 bf16;
typedef __bf16 bf16x8 __attribute__((ext_vector_type(8)));
typedef __bf16 bf16x4 __attribute__((ext_vector_type(4)));
typedef float f32x4 __attribute__((ext_vector_type(4)));

__device__ __forceinline__ void gload16(const void* g, void* l) {
  __builtin_amdgcn_global_load_lds((const __attribute__((address_space(1))) unsigned int*)g,
                                   (__attribute__((address_space(3))) unsigned int*)l,
                                   16, 0, 0);
}

// ---------------- casts (weights only) ----------------
__global__ void k_cast(const float* __restrict__ s, bf16* __restrict__ d, int n4) {
  int i = blockIdx.x * blockDim.x + threadIdx.x;
  if (i >= n4) return;
  float4 v = ((const float4*)s)[i];
  bf16x4 o = { (bf16)v.x, (bf16)v.y, (bf16)v.z, (bf16)v.w };
  ((bf16x4*)d)[i] = o;
}

// ---------------- V cast + relayout: V[e][d][r] -> Vb2[e][r/8][d][r%8] ----------------
__global__ void k_castv(const float* __restrict__ V, bf16* __restrict__ Vb2) {
  int id = blockIdx.x * 256 + threadIdx.x;
  int d = id & 1023;
  int rb = (id >> 10) & 7;
  int e = id >> 13;
  const float* src = V + ((size_t)(e * 1024 + d)) * 64 + rb * 8;
  float4 v0 = *(const float4*)src;
  float4 v1 = *(const float4*)(src + 4);
  bf16x8 o = { (bf16)v0.x, (bf16)v0.y, (bf16)v0.z, (bf16)v0.w,
               (bf16)v1.x, (bf16)v1.y, (bf16)v1.z, (bf16)v1.w };
  *(bf16x8*)(Vb2 + (size_t)id * 8) = o;
}

// ---------------- Gt2 = (W_gate @ W_enc)^T tiled [d/4][e][4]  (fp64 partials, atomic) ----------------
__global__ void k_gmat(const float* __restrict__ Wg, const float* __restrict__ We,
                       float* __restrict__ Gt2) {
  int d = blockIdx.x * 256 + threadIdx.x;
  int e = blockIdx.y;
  int j0 = blockIdx.z * 128;
  double a0 = 0.0, a1 = 0.0, a2 = 0.0, a3 = 0.0;
  for (int j = j0; j < j0 + 128; j += 4) {
    a0 += (double)Wg[e * D_DIM + j + 0] * (double)We[(size_t)(j + 0) * D_DIM + d];
    a1 += (double)Wg[e * D_DIM + j + 1] * (double)We[(size_t)(j + 1) * D_DIM + d];
    a2 += (double)Wg[e * D_DIM + j + 2] * (double)We[(size_t)(j + 2) * D_DIM + d];
    a3 += (double)Wg[e * D_DIM + j + 3] * (double)We[(size_t)(j + 3) * D_DIM + d];
  }
  atomicAdd(&Gt2[(d >> 2) * 64 + e * 4 + (d & 3)], (float)((a0 + a1) + (a2 + a3)));
}

// ---------------- bgate[e] = W_gate[e,:] . b_enc ----------------
__global__ void k_bgate(const float* __restrict__ Wg, const float* __restrict__ be,
                        float* __restrict__ bg) {
  __shared__ double red[256];
  int e = blockIdx.x, t = threadIdx.x;
  double a = 0.0;
  for (int j = t; j < D_DIM; j += 256) a += (double)Wg[e * D_DIM + j] * (double)be[j];
  red[t] = a; __syncthreads();
  for (int s = 128; s > 0; s >>= 1) { if (t < s) red[t] += red[t + s]; __syncthreads(); }
  if (t == 0) bg[e] = (float)red[0];
}

// ---------------- fused gating + x->bf16 cast (R16: chunked LDS-staged Gt2) ----------------
// R15 counters: VALUBusy 28%, Occ 33%, BW 18% -> stalled on per-wave Gt2
// L1/L2 streaming (each wave walked all 64KB of Gt2 with 1-deep prefetch).
// R16: block stages Gt2 in 8KB chunks, double-buffered (2x8KB LDS), via
// global_load_lds -- ONCE per block (4x less L2 traffic); compute reads LDS.
// G read addr = lane*16B (perfectly linear, conflict-free). One barrier per
// chunk (R13-proven dbuf pattern). Per-j FMA order bit-identical to R15.
__global__ __launch_bounds__(256) void k_gatecast(const float* __restrict__ x,
                                                  const float* __restrict__ Gt2,
                                                  const float* __restrict__ bg,
                                                  const float* __restrict__ gamma,
                                                  bf16* __restrict__ xb,
                                                  int* __restrict__ pk,
                                                  float2* __restrict__ wpair) {
  __shared__ float bufx[8][1024];   // 32KB: 8 token rows
  __shared__ float Gs[2][2048];     // 16KB: 2 x 8KB Gt2 chunks
  __shared__ float Ls[4 * 2 * NE];
  int tid = threadIdx.x;
  int wv = tid >> 6, lane = tid & 63;
  int g = lane & 15;
  int s = lane >> 4;
  int tokbase = blockIdx.x * 8 + wv * 2;

  // stage this wave's 2 token rows (8KB)
  const float* xr0 = x + (size_t)tokbase * D_DIM;
#pragma unroll
  for (int c = 0; c < 4; ++c) {
    gload16(xr0 + c * 256 + lane * 4, &bufx[wv * 2][c * 256 + lane * 4]);
    gload16(xr0 + D_DIM + c * 256 + lane * 4, &bufx[wv * 2 + 1][c * 256 + lane * 4]);
  }
  // stage Gt2 chunk 0 (floats [0,2048)): 256 threads x 2 float4
  gload16(Gt2 + tid * 4, &Gs[0][tid * 4]);
  gload16(Gt2 + 1024 + tid * 4, &Gs[0][1024 + tid * 4]);
  __syncthreads();   // drains all staging (vmcnt0) once

  const float* b0p = &bufx[wv * 2][s * 4];
  const float* b1p = &bufx[wv * 2 + 1][s * 4];
  float acc0 = 0.0f, acc1 = 0.0f;
  for (int c = 0; c < 8; ++c) {
    if (c < 7) {   // stage next chunk into other buffer
      const float* gsrc = Gt2 + (c + 1) * 2048;
      gload16(gsrc + tid * 4, &Gs[(c + 1) & 1][tid * 4]);
      gload16(gsrc + 1024 + tid * 4, &Gs[(c + 1) & 1][1024 + tid * 4]);
    }
    const float* gb = &Gs[c & 1][lane * 4];   // lane*16B: linear, conflict-free
    int itb = c * 8;
#pragma unroll
    for (int l = 0; l < 8; ++l) {
      float4 gv = *(const float4*)(gb + l * 256);
      float4 x0 = *(const float4*)(b0p + (itb + l) * 16);
      float4 x1 = *(const float4*)(b1p + (itb + l) * 16);
      acc0 += x0.x * gv.x + x0.y * gv.y + x0.z * gv.z + x0.w * gv.w;
      acc1 += x1.x * gv.x + x1.y * gv.y + x1.z * gv.z + x1.w * gv.w;
    }
    __syncthreads();   // drains next-chunk stage + buf-swap barrier
  }
  acc0 += __shfl_xor(acc0, 16); acc0 += __shfl_xor(acc0, 32);
  acc1 += __shfl_xor(acc1, 16); acc1 += __shfl_xor(acc1, 32);
  if (s == 0) {
    Ls[wv * 32 + g] = acc0;
    Ls[wv * 32 + 16 + g] = acc1;
  }

  // tail cast from LDS, coalesced bf16x4 stores
#pragma unroll
  for (int t = 0; t < 2; ++t) {
    const float4* src = (const float4*)&bufx[wv * 2 + t][0];
    bf16x4* dst = (bf16x4*)(xb + (size_t)(tokbase + t) * D_DIM);
#pragma unroll
    for (int r = 0; r < 4; ++r) {
      float4 v = src[lane + 64 * r];
      bf16x4 o = { (bf16)v.x, (bf16)v.y, (bf16)v.z, (bf16)v.w };
      dst[lane + 64 * r] = o;
    }
  }
  __syncthreads();

  if (lane < 2) {
    int t = lane;
    int tok = tokbase + t;
    const float* lrow = &Ls[wv * 32 + t * 16];
    float v1 = -1e30f, v2 = -1e30f; int i1 = 0, i2 = 0;
#pragma unroll
    for (int e = 0; e < NE; ++e) {
      float v = lrow[e] + bg[e];
      if (v > v1) { v2 = v1; i2 = i1; v1 = v; i1 = e; }
      else if (v > v2) { v2 = v; i2 = e; }
    }
    float e1 = expf(v2 - v1);
    float den = 1.0f + e1 + 1e-12f;
    float w0 = (1.0f / den) * gamma[i1];
    float w1 = (e1 / den) * gamma[i2];
    pk[tok] = i1 | (i2 << 8);
    wpair[tok] = make_float2(w0, w1);
  }
}

// ---------------- scatter: block-aggregated counting sort into per-bin lists ----------------
__global__ __launch_bounds__(256) void k_scatter(const int* __restrict__ pk,
                                                 const float2* __restrict__ wpair,
                                                 int* __restrict__ cnt,
                                                 int* __restrict__ lists,
                                                 float* __restrict__ wl) {
  __shared__ int lc[32];
  __shared__ int base[32];
  __shared__ int lc2[32];
  int tid = threadIdx.x;
  int tok = blockIdx.x * 256 + tid;
  if (tid < 32) { lc[tid] = 0; lc2[tid] = 0; }
  __syncthreads();
  int p = pk[tok];
  float2 w = wpair[tok];
  int b0 = p & 0xff;
  int b1 = 16 + ((p >> 8) & 0xff);
  atomicAdd(&lc[b0], 1);
  atomicAdd(&lc[b1], 1);
  __syncthreads();
  if (tid < 32 && lc[tid] > 0) base[tid] = atomicAdd(&cnt[tid], lc[tid]);
  __syncthreads();
  int r0 = base[b0] + atomicAdd(&lc2[b0], 1);
  lists[(size_t)b0 * NTOK + r0] = tok;
  wl[(size_t)b0 * NTOK + r0] = w.x;
  int r1 = base[b1] + atomicAdd(&lc2[b1], 1);
  lists[(size_t)b1 * NTOK + r1] = tok;
  wl[(size_t)b1 * NTOK + r1] = w.y;
}

// ---------------- block table: compact (bin, t0) list, one wave ----------------
__global__ void k_btab(const int* __restrict__ cnt, int2* __restrict__ btab,
                       int* __restrict__ nblk) {
  int lane = threadIdx.x;
  int nb = (lane < 32) ? ((cnt[lane] + 63) >> 6) : 0;
  int pfx = nb;
  for (int off = 1; off < 32; off <<= 1) {
    int v = __shfl_up(pfx, off);
    if (lane >= off) pfx += v;
  }
  int start = pfx - nb;
  if (lane < 32) {
    int c = cnt[lane];
    int i = 0;
    for (int t0 = 0; t0 < c; t0 += 64, ++i)
      btab[start + i] = make_int2(lane, t0);
  }
  if (lane == 31) *nblk = pfx;
}

// ---------------- encoder GEMM (R13, kept): 256x256, BK=32, dbuf, single-barrier ----------------
__global__ __launch_bounds__(512, 1) void k_encgemm(const bf16* __restrict__ A,
                                                    const bf16* __restrict__ W,
                                                    const float* __restrict__ bias,
                                                    bf16* __restrict__ encb) {
  __shared__ char smem[65536];
  bf16* const AsB = (bf16*)smem;
  bf16* const BsB = (bf16*)(smem + 32768);
  int tid = threadIdx.x;
  int w = blockIdx.x;
  int bm = (w & 63) * 256;
  int bn = (w >> 6) * 256;
  int lane = tid & 63, wv = tid >> 6;
  int wm = (wv >> 2) * 128, wn = (wv & 3) * 64;
  int srow = tid >> 2;
  int sc = (tid & 3) * 8;
  int fr = lane & 15, fk = (lane >> 4) * 8;
  f32x4 acc[8][4] = {};

  {
    bf16* as = AsB; bf16* bs = BsB;
    gload16(A + (size_t)(bm + srow) * D_DIM + sc, &as[srow * 32 + sc]);
    gload16(A + (size_t)(bm + 128 + srow) * D_DIM + sc, &as[(128 + srow) * 32 + sc]);
    gload16(W + (size_t)(bn + srow) * D_DIM + sc, &bs[srow * 32 + sc]);
    gload16(W + (size_t)(bn + 128 + srow) * D_DIM + sc, &bs[(128 + srow) * 32 + sc]);
  }
  __syncthreads();

  for (int k0 = 0; k0 < D_DIM; k0 += 32) {
    int cur = (k0 >> 5) & 1;
    if (k0 + 32 < D_DIM) {
      int kn = k0 + 32;
      bf16* as = AsB + (cur ^ 1) * 8192;
      bf16* bs = BsB + (cur ^ 1) * 8192;
      gload16(A + (size_t)(bm + srow) * D_DIM + kn + sc, &as[srow * 32 + sc]);
      gload16(A + (size_t)(bm + 128 + srow) * D_DIM + kn + sc, &as[(128 + srow) * 32 + sc]);
      gload16(W + (size_t)(bn + srow) * D_DIM + kn + sc, &bs[srow * 32 + sc]);
      gload16(W + (size_t)(bn + 128 + srow) * D_DIM + kn + sc, &bs[(128 + srow) * 32 + sc]);
    }
    const bf16* as = AsB + cur * 8192;
    const bf16* bs = BsB + cur * 8192;
    bf16x8 af[8], bv[4];
#pragma unroll
    for (int m = 0; m < 8; ++m)
      af[m] = *(const bf16x8*)&as[(wm + m * 16 + fr) * 32 + fk];
#pragma unroll
    for (int n = 0; n < 4; ++n)
      bv[n] = *(const bf16x8*)&bs[(wn + n * 16 + fr) * 32 + fk];
#pragma unroll
    for (int m = 0; m < 8; ++m)
#pragma unroll
      for (int n = 0; n < 4; ++n)
        acc[m][n] = __builtin_amdgcn_mfma_f32_16x16x32_bf16(af[m], bv[n], acc[m][n], 0, 0, 0);
    __syncthreads();
  }

  int rg = (lane >> 4) * 4;
  bf16* tb = (bf16*)smem + wv * 2176;
#pragma unroll
  for (int h = 0; h < 4; ++h) {
#pragma unroll
    for (int mi = 0; mi < 2; ++mi) {
      int m = h * 2 + mi;
#pragma unroll
      for (int n = 0; n < 4; ++n) {
        float bval = bias[bn + wn + n * 16 + fr];
#pragma unroll
        for (int r = 0; r < 4; ++r)
          tb[(mi * 16 + rg + r) * 68 + n * 16 + fr] = (bf16)(acc[m][n][r] + bval);
      }
    }
#pragma unroll
    for (int it2 = 0; it2 < 8; ++it2) {
      int row = it2 * 4 + (lane >> 4);
      int c4 = (lane & 15) * 4;
      *(ushort4*)&encb[(size_t)(bm + wm + h * 32 + row) * D_DIM + bn + wn + c4] =
        *(const ushort4*)&tb[row * 68 + c4];
    }
  }
}

// ---------------- expert kernel (R15, kept): swizzled reads + coalesced epilogue ----------------
__global__ __launch_bounds__(256) void k_expert(const bf16* __restrict__ encb,
                                                const bf16* __restrict__ Ub,
                                                const bf16* __restrict__ Vb2,
                                                const int* __restrict__ cnt,
                                                const int* __restrict__ lists,
                                                const float* __restrict__ wl,
                                                const int2* __restrict__ btab,
                                                const int* __restrict__ nblk,
                                                bf16* __restrict__ d0,
                                                bf16* __restrict__ d1) {
  int bid = blockIdx.x;
  if (bid >= *nblk) return;
  int2 bt = btab[bid];
  int bin = bt.x, t0 = bt.y;
  int slot = bin >> 4, e = bin & 15;
  int c = cnt[bin];
  int nrows = c - t0; if (nrows > 64) nrows = 64;
  const int* tl = lists + (size_t)bin * NTOK + t0;
  const float* wlp = wl + (size_t)bin * NTOK + t0;

  __shared__ int toks[64];
  __shared__ float coefs[64];
  __shared__ bf16 AU[8192];
  __shared__ bf16 Ss[64 * 64];
  bf16* const As = AU;
  bf16* const Us = AU + 4096;

  int tid = threadIdx.x;
  if (tid < 64) {
    int rr = tid < nrows ? tid : nrows - 1;
    toks[tid] = tl[rr];
    coefs[tid] = tid < nrows ? wlp[tid] : 0.0f;
  }
  __syncthreads();

  int lane = tid & 63, wv = tid >> 6;
  int srow = tid >> 3;
  int sc8 = tid & 7;
  int scol = sc8 * 8;
  int cs = (sc8 ^ (srow & 7)) * 8;
  int fr = lane & 15, fk = (lane >> 4) * 8;
  int sw = (fr & 7) << 3;
  size_t tokA0 = (size_t)toks[srow] * D_DIM;
  size_t tokA1 = (size_t)toks[32 + srow] * D_DIM;
  const bf16* Ue = Ub + (size_t)e * RK * D_DIM;
  f32x4 acc1[4] = {};

  for (int k0 = 0; k0 < D_DIM; k0 += 64) {
    __syncthreads();
    gload16(encb + tokA0 + k0 + cs, &As[srow * 64 + scol]);
    gload16(encb + tokA1 + k0 + cs, &As[(32 + srow) * 64 + scol]);
    gload16(Ue + (size_t)srow * D_DIM + k0 + cs, &Us[srow * 64 + scol]);
    gload16(Ue + (size_t)(32 + srow) * D_DIM + k0 + cs, &Us[(32 + srow) * 64 + scol]);
    __syncthreads();
#pragma unroll
    for (int kk = 0; kk < 2; ++kk) {
      bf16x8 af = *(const bf16x8*)&As[((wv * 16 + fr) * 64 + kk * 32 + fk) ^ sw];
#pragma unroll
      for (int n = 0; n < 4; ++n) {
        bf16x8 bv = *(const bf16x8*)&Us[((n * 16 + fr) * 64 + kk * 32 + fk) ^ sw];
        acc1[n] = __builtin_amdgcn_mfma_f32_16x16x32_bf16(af, bv, acc1[n], 0, 0, 0);
      }
    }
  }
  int rg = (lane >> 4) * 4;
#pragma unroll
  for (int n = 0; n < 4; ++n)
#pragma unroll
    for (int r = 0; r < 4; ++r) {
      int row = wv * 16 + rg + r;
      float v = acc1[n][r];
      float s = v / (1.0f + __expf(-v));
      Ss[(row * 64 + n * 16 + fr) ^ (((rg + r) & 7) << 3)] = (bf16)(s * coefs[row]);
    }
  __syncthreads();
  bf16x8 a2[4][2];
#pragma unroll
  for (int m = 0; m < 4; ++m)
#pragma unroll
    for (int kk = 0; kk < 2; ++kk)
      a2[m][kk] = *(const bf16x8*)&Ss[((m * 16 + fr) * 64 + kk * 32 + fk) ^ sw];
  __syncthreads();

  const bf16* Ve2 = Vb2 + (size_t)e * RK * D_DIM;
  bf16* dst = slot ? d1 : d0;
  int rb0 = lane >> 4;
  int colbase = wv * 256;
  bf16* tb = AU + wv * 2048;
  for (int njb = 0; njb < 8; ++njb) {
#pragma unroll
    for (int nj2 = 0; nj2 < 2; ++nj2) {
      int nj = njb * 2 + nj2;
      int dcol = colbase + nj * 16 + fr;
      bf16x8 b0 = *(const bf16x8*)&Ve2[((size_t)rb0 * D_DIM + dcol) * 8];
      bf16x8 b1 = *(const bf16x8*)&Ve2[((size_t)(rb0 + 4) * D_DIM + dcol) * 8];
#pragma unroll
      for (int m = 0; m < 4; ++m) {
        f32x4 a = {};
        a = __builtin_amdgcn_mfma_f32_16x16x32_bf16(a2[m][0], b0, a, 0, 0, 0);
        a = __builtin_amdgcn_mfma_f32_16x16x32_bf16(a2[m][1], b1, a, 0, 0, 0);
#pragma unroll
        for (int r = 0; r < 4; ++r)
          tb[(m * 16 + rg + r) * 32 + nj2 * 16 + fr] = (bf16)a[r];
      }
    }
#pragma unroll
    for (int it2 = 0; it2 < 16; ++it2) {
      int row = it2 * 4 + (lane >> 4);
      int c2 = (lane & 15) * 2;
      if (row < nrows)
        *(ushort2*)&dst[(size_t)toks[row] * D_DIM + colbase + njb * 32 + c2] =
          *(const ushort2*)&tb[row * 32 + c2];
    }
  }
}

// ---------------- final: out = encb + d0 + d1 (pure streams, no RMW) ----------------
__global__ __launch_bounds__(256) void k_final(float* __restrict__ out,
                                               const bf16* __restrict__ encb,
                                               const bf16* __restrict__ d0,
                                               const bf16* __restrict__ d1) {
  size_t i = ((size_t)blockIdx.x * 256 + threadIdx.x) * 8;
  bf16x8 e = *(const bf16x8*)(encb + i);
  bf16x8 a = *(const bf16x8*)(d0 + i);
  bf16x8 b = *(const bf16x8*)(d1 + i);
  float4 o0, o1;
  o0.x = (float)e[0] + (float)a[0] + (float)b[0];
  o0.y = (float)e[1] + (float)a[1] + (float)b[1];
  o0.z = (float)e[2] + (float)a[2] + (float)b[2];
  o0.w = (float)e[3] + (float)a[3] + (float)b[3];
  o1.x = (float)e[4] + (float)a[4] + (float)b[4];
  o1.y = (float)e[5] + (float)a[5] + (float)b[5];
  o1.z = (float)e[6] + (float)a[6] + (float)b[6];
  o1.w = (float)e[7] + (float)a[7] + (float)b[7];
  *(float4*)(out + i) = o0;
  *(float4*)(out + i + 4) = o1;
}

extern "C" void kernel_launch(void* const* d_in, const int* in_sizes, int n_in,
                              void* d_out, int out_size, void* d_ws, size_t ws_size,
                              hipStream_t stream) {
  const float* x   = (const float*)d_in[0];
  const float* We  = (const float*)d_in[1];
  const float* be  = (const float*)d_in[2];
  const float* Wg  = (const float*)d_in[3];
  const float* U   = (const float*)d_in[4];
  const float* V   = (const float*)d_in[5];
  const float* gam = (const float*)d_in[6];
  float* out = (float*)d_out;
  char* ws = (char*)d_ws;

  int*    cnt  = (int*)(ws + 0);
  float*  Gt2  = (float*)(ws + 256);
  float*  bg   = (float*)(ws + 66048);
  int2*   btab = (int2*)(ws + 66176);
  int*    nblk = (int*)(ws + 70656);
  bf16*   xb   = (bf16*)(ws + 131072);
  bf16*   d0   = (bf16*)(ws + 131072);
  bf16*   encb = (bf16*)(ws + 131072 + 33554432);
  char*   base = ws + 131072 + 2 * 33554432;
  bf16*   Wb   = (bf16*)(base);
  bf16*   Ubf  = (bf16*)(base + 2097152);
  bf16*   Vb2  = (bf16*)(base + 2 * 2097152);
  int*    lists= (int*)(base + 3 * 2097152);
  float*  wl   = (float*)(base + 4 * 2097152);
  int*    pk   = (int*)(base + 5 * 2097152);
  float2* wpr  = (float2*)(base + 5 * 2097152 + 131072);
  bf16*   d1   = (bf16*)(base + 5 * 2097152 + 131072 + 131072 + 131072);

  hipMemsetAsync(ws, 0, 66048, stream);

  k_cast<<<1024, 256, 0, stream>>>(We, Wb, 1048576 / 4);
  k_cast<<<1024, 256, 0, stream>>>(U, Ubf, 1048576 / 4);
  k_castv<<<512, 256, 0, stream>>>(V, Vb2);

  dim3 gg(4, 16, 8);
  k_gmat<<<gg, 256, 0, stream>>>(Wg, We, Gt2);
  k_bgate<<<16, 256, 0, stream>>>(Wg, be, bg);

  k_gatecast<<<2048, 256, 0, stream>>>(x, Gt2, bg, gam, xb, pk, wpr);
  k_scatter<<<64, 256, 0, stream>>>(pk, wpr, cnt, lists, wl);
  k_btab<<<1, 64, 0, stream>>>(cnt, btab, nblk);

  k_encgemm<<<256, 512, 0, stream>>>(xb, Wb, be, encb);

  k_expert<<<544, 256, 0, stream>>>(encb, Ubf, Vb2, cnt, lists, wl, btab, nblk, d0, d1);
  k_final<<<8192, 256, 0, stream>>>(out, encb, d0, d1);
}

// Round 17
// 160.820 us; speedup vs baseline: 1.0424x; 1.0424x over previous
//
#include <hip/hip_runtime.h>
#include <hip/hip_bf16.h>

#define D_DIM 1024
#define NE 16
#define RK 64
#define NTOK 16384

typedef __bf16 bf16;
typedef __bf16 bf16x8 __attribute__((ext_vector_type(8)));
typedef __bf16 bf16x4 __attribute__((ext_vector_type(4)));
typedef float f32x4 __attribute__((ext_vector_type(4)));

__device__ __forceinline__ void gload16(const void* g, void* l) {
  __builtin_amdgcn_global_load_lds((const __attribute__((address_space(1))) unsigned int*)g,
                                   (__attribute__((address_space(3))) unsigned int*)l,
                                   16, 0, 0);
}

// ---------------- casts (weights only) ----------------
__global__ void k_cast(const float* __restrict__ s, bf16* __restrict__ d, int n4) {
  int i = blockIdx.x * blockDim.x + threadIdx.x;
  if (i >= n4) return;
  float4 v = ((const float4*)s)[i];
  bf16x4 o = { (bf16)v.x, (bf16)v.y, (bf16)v.z, (bf16)v.w };
  ((bf16x4*)d)[i] = o;
}

// ---------------- V cast + relayout: V[e][d][r] -> Vb2[e][r/8][d][r%8] ----------------
__global__ void k_castv(const float* __restrict__ V, bf16* __restrict__ Vb2) {
  int id = blockIdx.x * 256 + threadIdx.x;
  int d = id & 1023;
  int rb = (id >> 10) & 7;
  int e = id >> 13;
  const float* src = V + ((size_t)(e * 1024 + d)) * 64 + rb * 8;
  float4 v0 = *(const float4*)src;
  float4 v1 = *(const float4*)(src + 4);
  bf16x8 o = { (bf16)v0.x, (bf16)v0.y, (bf16)v0.z, (bf16)v0.w,
               (bf16)v1.x, (bf16)v1.y, (bf16)v1.z, (bf16)v1.w };
  *(bf16x8*)(Vb2 + (size_t)id * 8) = o;
}

// ---------------- Gt2 = (W_gate @ W_enc)^T tiled [d/4][e][4]  (fp64 partials, atomic) ----------------
__global__ void k_gmat(const float* __restrict__ Wg, const float* __restrict__ We,
                       float* __restrict__ Gt2) {
  int d = blockIdx.x * 256 + threadIdx.x;
  int e = blockIdx.y;
  int j0 = blockIdx.z * 128;
  double a0 = 0.0, a1 = 0.0, a2 = 0.0, a3 = 0.0;
  for (int j = j0; j < j0 + 128; j += 4) {
    a0 += (double)Wg[e * D_DIM + j + 0] * (double)We[(size_t)(j + 0) * D_DIM + d];
    a1 += (double)Wg[e * D_DIM + j + 1] * (double)We[(size_t)(j + 1) * D_DIM + d];
    a2 += (double)Wg[e * D_DIM + j + 2] * (double)We[(size_t)(j + 2) * D_DIM + d];
    a3 += (double)Wg[e * D_DIM + j + 3] * (double)We[(size_t)(j + 3) * D_DIM + d];
  }
  atomicAdd(&Gt2[(d >> 2) * 64 + e * 4 + (d & 3)], (float)((a0 + a1) + (a2 + a3)));
}

// ---------------- bgate[e] = W_gate[e,:] . b_enc ----------------
__global__ void k_bgate(const float* __restrict__ Wg, const float* __restrict__ be,
                        float* __restrict__ bg) {
  __shared__ double red[256];
  int e = blockIdx.x, t = threadIdx.x;
  double a = 0.0;
  for (int j = t; j < D_DIM; j += 256) a += (double)Wg[e * D_DIM + j] * (double)be[j];
  red[t] = a; __syncthreads();
  for (int s = 128; s > 0; s >>= 1) { if (t < s) red[t] += red[t + s]; __syncthreads(); }
  if (t == 0) bg[e] = (float)red[0];
}

// ---------------- fused gating + x->bf16 cast (R17: R15 base + 4-deep G prefetch) ----------------
// R16 post-mortem: Gt2 LDS staging REGRESSED (49.7KB LDS -> 3 blk/CU; barriers
// added sync without removing the stall). Reverted. R15 arithmetic showed
// ~500cy/iter = one exposed L2 round-trip: the 1-deep G prefetch keeps only
// ONE load in flight. R17: 4-deep software pipeline with statically-named
// float4 regs (rule #20: no runtime-indexed arrays). FMA order bit-identical
// to R15 (sequential it, same chains).
__global__ __launch_bounds__(256) void k_gatecast(const float* __restrict__ x,
                                                  const float* __restrict__ Gt2,
                                                  const float* __restrict__ bg,
                                                  const float* __restrict__ gamma,
                                                  bf16* __restrict__ xb,
                                                  int* __restrict__ pk,
                                                  float2* __restrict__ wpair) {
  __shared__ float bufx[8][1024];
  __shared__ float Ls[4 * 2 * NE];
  int tid = threadIdx.x;
  int wv = tid >> 6, lane = tid & 63;
  int g = lane & 15;
  int s = lane >> 4;
  int tokbase = blockIdx.x * 8 + wv * 2;

  const float* xr0 = x + (size_t)tokbase * D_DIM;
#pragma unroll
  for (int c = 0; c < 4; ++c) {
    gload16(xr0 + c * 256 + lane * 4, &bufx[wv * 2][c * 256 + lane * 4]);
    gload16(xr0 + D_DIM + c * 256 + lane * 4, &bufx[wv * 2 + 1][c * 256 + lane * 4]);
  }

  const float* Gq = Gt2 + s * 64 + g * 4;      // + it*256 floats per iter
  const float* b0p = &bufx[wv * 2][s * 4];
  const float* b1p = &bufx[wv * 2 + 1][s * 4];
  float acc0 = 0.0f, acc1 = 0.0f;
  // 4-deep prefetch: ga..gd cover iters base..base+3; na..nd fetch base+4..base+7
  float4 ga = *(const float4*)(Gq + 0 * 256);
  float4 gb = *(const float4*)(Gq + 1 * 256);
  float4 gc = *(const float4*)(Gq + 2 * 256);
  float4 gd = *(const float4*)(Gq + 3 * 256);
  for (int c = 0; c < 16; ++c) {
    int base = c * 4;
    int nb = (c < 15) ? base + 4 : base;   // last-group reloads (discarded)
    float4 na = *(const float4*)(Gq + (size_t)(nb + 0) * 256);
    float4 nb4 = *(const float4*)(Gq + (size_t)(nb + 1) * 256);
    float4 nc = *(const float4*)(Gq + (size_t)(nb + 2) * 256);
    float4 nd = *(const float4*)(Gq + (size_t)(nb + 3) * 256);
#define GSTEP(GV, J)                                                        \
    {                                                                       \
      float4 x0 = *(const float4*)(b0p + (base + (J)) * 16);                \
      float4 x1 = *(const float4*)(b1p + (base + (J)) * 16);                \
      acc0 += x0.x * GV.x + x0.y * GV.y + x0.z * GV.z + x0.w * GV.w;        \
      acc1 += x1.x * GV.x + x1.y * GV.y + x1.z * GV.z + x1.w * GV.w;        \
    }
    GSTEP(ga, 0) GSTEP(gb, 1) GSTEP(gc, 2) GSTEP(gd, 3)
#undef GSTEP
    ga = na; gb = nb4; gc = nc; gd = nd;
  }
  acc0 += __shfl_xor(acc0, 16); acc0 += __shfl_xor(acc0, 32);
  acc1 += __shfl_xor(acc1, 16); acc1 += __shfl_xor(acc1, 32);
  if (s == 0) {
    Ls[wv * 32 + g] = acc0;
    Ls[wv * 32 + 16 + g] = acc1;
  }

  // tail cast from LDS, coalesced bf16x4 stores
#pragma unroll
  for (int t = 0; t < 2; ++t) {
    const float4* src = (const float4*)&bufx[wv * 2 + t][0];
    bf16x4* dst = (bf16x4*)(xb + (size_t)(tokbase + t) * D_DIM);
#pragma unroll
    for (int r = 0; r < 4; ++r) {
      float4 v = src[lane + 64 * r];
      bf16x4 o = { (bf16)v.x, (bf16)v.y, (bf16)v.z, (bf16)v.w };
      dst[lane + 64 * r] = o;
    }
  }
  __syncthreads();

  if (lane < 2) {
    int t = lane;
    int tok = tokbase + t;
    const float* lrow = &Ls[wv * 32 + t * 16];
    float v1 = -1e30f, v2 = -1e30f; int i1 = 0, i2 = 0;
#pragma unroll
    for (int e = 0; e < NE; ++e) {
      float v = lrow[e] + bg[e];
      if (v > v1) { v2 = v1; i2 = i1; v1 = v; i1 = e; }
      else if (v > v2) { v2 = v; i2 = e; }
    }
    float e1 = expf(v2 - v1);
    float den = 1.0f + e1 + 1e-12f;
    float w0 = (1.0f / den) * gamma[i1];
    float w1 = (e1 / den) * gamma[i2];
    pk[tok] = i1 | (i2 << 8);
    wpair[tok] = make_float2(w0, w1);
  }
}

// ---------------- scatter: block-aggregated counting sort into per-bin lists ----------------
__global__ __launch_bounds__(256) void k_scatter(const int* __restrict__ pk,
                                                 const float2* __restrict__ wpair,
                                                 int* __restrict__ cnt,
                                                 int* __restrict__ lists,
                                                 float* __restrict__ wl) {
  __shared__ int lc[32];
  __shared__ int base[32];
  __shared__ int lc2[32];
  int tid = threadIdx.x;
  int tok = blockIdx.x * 256 + tid;
  if (tid < 32) { lc[tid] = 0; lc2[tid] = 0; }
  __syncthreads();
  int p = pk[tok];
  float2 w = wpair[tok];
  int b0 = p & 0xff;
  int b1 = 16 + ((p >> 8) & 0xff);
  atomicAdd(&lc[b0], 1);
  atomicAdd(&lc[b1], 1);
  __syncthreads();
  if (tid < 32 && lc[tid] > 0) base[tid] = atomicAdd(&cnt[tid], lc[tid]);
  __syncthreads();
  int r0 = base[b0] + atomicAdd(&lc2[b0], 1);
  lists[(size_t)b0 * NTOK + r0] = tok;
  wl[(size_t)b0 * NTOK + r0] = w.x;
  int r1 = base[b1] + atomicAdd(&lc2[b1], 1);
  lists[(size_t)b1 * NTOK + r1] = tok;
  wl[(size_t)b1 * NTOK + r1] = w.y;
}

// ---------------- block table: compact (bin, t0) list, one wave ----------------
__global__ void k_btab(const int* __restrict__ cnt, int2* __restrict__ btab,
                       int* __restrict__ nblk) {
  int lane = threadIdx.x;
  int nb = (lane < 32) ? ((cnt[lane] + 63) >> 6) : 0;
  int pfx = nb;
  for (int off = 1; off < 32; off <<= 1) {
    int v = __shfl_up(pfx, off);
    if (lane >= off) pfx += v;
  }
  int start = pfx - nb;
  if (lane < 32) {
    int c = cnt[lane];
    int i = 0;
    for (int t0 = 0; t0 < c; t0 += 64, ++i)
      btab[start + i] = make_int2(lane, t0);
  }
  if (lane == 31) *nblk = pfx;
}

// ---------------- encoder GEMM (R13, kept): 256x256, BK=32, dbuf, single-barrier ----------------
__global__ __launch_bounds__(512, 1) void k_encgemm(const bf16* __restrict__ A,
                                                    const bf16* __restrict__ W,
                                                    const float* __restrict__ bias,
                                                    bf16* __restrict__ encb) {
  __shared__ char smem[65536];
  bf16* const AsB = (bf16*)smem;
  bf16* const BsB = (bf16*)(smem + 32768);
  int tid = threadIdx.x;
  int w = blockIdx.x;
  int bm = (w & 63) * 256;
  int bn = (w >> 6) * 256;
  int lane = tid & 63, wv = tid >> 6;
  int wm = (wv >> 2) * 128, wn = (wv & 3) * 64;
  int srow = tid >> 2;
  int sc = (tid & 3) * 8;
  int fr = lane & 15, fk = (lane >> 4) * 8;
  f32x4 acc[8][4] = {};

  {
    bf16* as = AsB; bf16* bs = BsB;
    gload16(A + (size_t)(bm + srow) * D_DIM + sc, &as[srow * 32 + sc]);
    gload16(A + (size_t)(bm + 128 + srow) * D_DIM + sc, &as[(128 + srow) * 32 + sc]);
    gload16(W + (size_t)(bn + srow) * D_DIM + sc, &bs[srow * 32 + sc]);
    gload16(W + (size_t)(bn + 128 + srow) * D_DIM + sc, &bs[(128 + srow) * 32 + sc]);
  }
  __syncthreads();

  for (int k0 = 0; k0 < D_DIM; k0 += 32) {
    int cur = (k0 >> 5) & 1;
    if (k0 + 32 < D_DIM) {
      int kn = k0 + 32;
      bf16* as = AsB + (cur ^ 1) * 8192;
      bf16* bs = BsB + (cur ^ 1) * 8192;
      gload16(A + (size_t)(bm + srow) * D_DIM + kn + sc, &as[srow * 32 + sc]);
      gload16(A + (size_t)(bm + 128 + srow) * D_DIM + kn + sc, &as[(128 + srow) * 32 + sc]);
      gload16(W + (size_t)(bn + srow) * D_DIM + kn + sc, &bs[srow * 32 + sc]);
      gload16(W + (size_t)(bn + 128 + srow) * D_DIM + kn + sc, &bs[(128 + srow) * 32 + sc]);
    }
    const bf16* as = AsB + cur * 8192;
    const bf16* bs = BsB + cur * 8192;
    bf16x8 af[8], bv[4];
#pragma unroll
    for (int m = 0; m < 8; ++m)
      af[m] = *(const bf16x8*)&as[(wm + m * 16 + fr) * 32 + fk];
#pragma unroll
    for (int n = 0; n < 4; ++n)
      bv[n] = *(const bf16x8*)&bs[(wn + n * 16 + fr) * 32 + fk];
#pragma unroll
    for (int m = 0; m < 8; ++m)
#pragma unroll
      for (int n = 0; n < 4; ++n)
        acc[m][n] = __builtin_amdgcn_mfma_f32_16x16x32_bf16(af[m], bv[n], acc[m][n], 0, 0, 0);
    __syncthreads();
  }

  int rg = (lane >> 4) * 4;
  bf16* tb = (bf16*)smem + wv * 2176;
#pragma unroll
  for (int h = 0; h < 4; ++h) {
#pragma unroll
    for (int mi = 0; mi < 2; ++mi) {
      int m = h * 2 + mi;
#pragma unroll
      for (int n = 0; n < 4; ++n) {
        float bval = bias[bn + wn + n * 16 + fr];
#pragma unroll
        for (int r = 0; r < 4; ++r)
          tb[(mi * 16 + rg + r) * 68 + n * 16 + fr] = (bf16)(acc[m][n][r] + bval);
      }
    }
#pragma unroll
    for (int it2 = 0; it2 < 8; ++it2) {
      int row = it2 * 4 + (lane >> 4);
      int c4 = (lane & 15) * 4;
      *(ushort4*)&encb[(size_t)(bm + wm + h * 32 + row) * D_DIM + bn + wn + c4] =
        *(const ushort4*)&tb[row * 68 + c4];
    }
  }
}

// ---------------- expert kernel (R15, kept): swizzled reads + coalesced epilogue ----------------
__global__ __launch_bounds__(256) void k_expert(const bf16* __restrict__ encb,
                                                const bf16* __restrict__ Ub,
                                                const bf16* __restrict__ Vb2,
                                                const int* __restrict__ cnt,
                                                const int* __restrict__ lists,
                                                const float* __restrict__ wl,
                                                const int2* __restrict__ btab,
                                                const int* __restrict__ nblk,
                                                bf16* __restrict__ d0,
                                                bf16* __restrict__ d1) {
  int bid = blockIdx.x;
  if (bid >= *nblk) return;
  int2 bt = btab[bid];
  int bin = bt.x, t0 = bt.y;
  int slot = bin >> 4, e = bin & 15;
  int c = cnt[bin];
  int nrows = c - t0; if (nrows > 64) nrows = 64;
  const int* tl = lists + (size_t)bin * NTOK + t0;
  const float* wlp = wl + (size_t)bin * NTOK + t0;

  __shared__ int toks[64];
  __shared__ float coefs[64];
  __shared__ bf16 AU[8192];
  __shared__ bf16 Ss[64 * 64];
  bf16* const As = AU;
  bf16* const Us = AU + 4096;

  int tid = threadIdx.x;
  if (tid < 64) {
    int rr = tid < nrows ? tid : nrows - 1;
    toks[tid] = tl[rr];
    coefs[tid] = tid < nrows ? wlp[tid] : 0.0f;
  }
  __syncthreads();

  int lane = tid & 63, wv = tid >> 6;
  int srow = tid >> 3;
  int sc8 = tid & 7;
  int scol = sc8 * 8;
  int cs = (sc8 ^ (srow & 7)) * 8;
  int fr = lane & 15, fk = (lane >> 4) * 8;
  int sw = (fr & 7) << 3;
  size_t tokA0 = (size_t)toks[srow] * D_DIM;
  size_t tokA1 = (size_t)toks[32 + srow] * D_DIM;
  const bf16* Ue = Ub + (size_t)e * RK * D_DIM;
  f32x4 acc1[4] = {};

  for (int k0 = 0; k0 < D_DIM; k0 += 64) {
    __syncthreads();
    gload16(encb + tokA0 + k0 + cs, &As[srow * 64 + scol]);
    gload16(encb + tokA1 + k0 + cs, &As[(32 + srow) * 64 + scol]);
    gload16(Ue + (size_t)srow * D_DIM + k0 + cs, &Us[srow * 64 + scol]);
    gload16(Ue + (size_t)(32 + srow) * D_DIM + k0 + cs, &Us[(32 + srow) * 64 + scol]);
    __syncthreads();
#pragma unroll
    for (int kk = 0; kk < 2; ++kk) {
      bf16x8 af = *(const bf16x8*)&As[((wv * 16 + fr) * 64 + kk * 32 + fk) ^ sw];
#pragma unroll
      for (int n = 0; n < 4; ++n) {
        bf16x8 bv = *(const bf16x8*)&Us[((n * 16 + fr) * 64 + kk * 32 + fk) ^ sw];
        acc1[n] = __builtin_amdgcn_mfma_f32_16x16x32_bf16(af, bv, acc1[n], 0, 0, 0);
      }
    }
  }
  int rg = (lane >> 4) * 4;
#pragma unroll
  for (int n = 0; n < 4; ++n)
#pragma unroll
    for (int r = 0; r < 4; ++r) {
      int row = wv * 16 + rg + r;
      float v = acc1[n][r];
      float s = v / (1.0f + __expf(-v));
      Ss[(row * 64 + n * 16 + fr) ^ (((rg + r) & 7) << 3)] = (bf16)(s * coefs[row]);
    }
  __syncthreads();
  bf16x8 a2[4][2];
#pragma unroll
  for (int m = 0; m < 4; ++m)
#pragma unroll
    for (int kk = 0; kk < 2; ++kk)
      a2[m][kk] = *(const bf16x8*)&Ss[((m * 16 + fr) * 64 + kk * 32 + fk) ^ sw];
  __syncthreads();

  const bf16* Ve2 = Vb2 + (size_t)e * RK * D_DIM;
  bf16* dst = slot ? d1 : d0;
  int rb0 = lane >> 4;
  int colbase = wv * 256;
  bf16* tb = AU + wv * 2048;
  for (int njb = 0; njb < 8; ++njb) {
#pragma unroll
    for (int nj2 = 0; nj2 < 2; ++nj2) {
      int nj = njb * 2 + nj2;
      int dcol = colbase + nj * 16 + fr;
      bf16x8 b0 = *(const bf16x8*)&Ve2[((size_t)rb0 * D_DIM + dcol) * 8];
      bf16x8 b1 = *(const bf16x8*)&Ve2[((size_t)(rb0 + 4) * D_DIM + dcol) * 8];
#pragma unroll
      for (int m = 0; m < 4; ++m) {
        f32x4 a = {};
        a = __builtin_amdgcn_mfma_f32_16x16x32_bf16(a2[m][0], b0, a, 0, 0, 0);
        a = __builtin_amdgcn_mfma_f32_16x16x32_bf16(a2[m][1], b1, a, 0, 0, 0);
#pragma unroll
        for (int r = 0; r < 4; ++r)
          tb[(m * 16 + rg + r) * 32 + nj2 * 16 + fr] = (bf16)a[r];
      }
    }
#pragma unroll
    for (int it2 = 0; it2 < 16; ++it2) {
      int row = it2 * 4 + (lane >> 4);
      int c2 = (lane & 15) * 2;
      if (row < nrows)
        *(ushort2*)&dst[(size_t)toks[row] * D_DIM + colbase + njb * 32 + c2] =
          *(const ushort2*)&tb[row * 32 + c2];
    }
  }
}

// ---------------- final: out = encb + d0 + d1 (pure streams, no RMW) ----------------
__global__ __launch_bounds__(256) void k_final(float* __restrict__ out,
                                               const bf16* __restrict__ encb,
                                               const bf16* __restrict__ d0,
                                               const bf16* __restrict__ d1) {
  size_t i = ((size_t)blockIdx.x * 256 + threadIdx.x) * 8;
  bf16x8 e = *(const bf16x8*)(encb + i);
  bf16x8 a = *(const bf16x8*)(d0 + i);
  bf16x8 b = *(const bf16x8*)(d1 + i);
  float4 o0, o1;
  o0.x = (float)e[0] + (float)a[0] + (float)b[0];
  o0.y = (float)e[1] + (float)a[1] + (float)b[1];
  o0.z = (float)e[2] + (float)a[2] + (float)b[2];
  o0.w = (float)e[3] + (float)a[3] + (float)b[3];
  o1.x = (float)e[4] + (float)a[4] + (float)b[4];
  o1.y = (float)e[5] + (float)a[5] + (float)b[5];
  o1.z = (float)e[6] + (float)a[6] + (float)b[6];
  o1.w = (float)e[7] + (float)a[7] + (float)b[7];
  *(float4*)(out + i) = o0;
  *(float4*)(out + i + 4) = o1;
}

extern "C" void kernel_launch(void* const* d_in, const int* in_sizes, int n_in,
                              void* d_out, int out_size, void* d_ws, size_t ws_size,
                              hipStream_t stream) {
  const float* x   = (const float*)d_in[0];
  const float* We  = (const float*)d_in[1];
  const float* be  = (const float*)d_in[2];
  const float* Wg  = (const float*)d_in[3];
  const float* U   = (const float*)d_in[4];
  const float* V   = (const float*)d_in[5];
  const float* gam = (const float*)d_in[6];
  float* out = (float*)d_out;
  char* ws = (char*)d_ws;

  int*    cnt  = (int*)(ws + 0);
  float*  Gt2  = (float*)(ws + 256);
  float*  bg   = (float*)(ws + 66048);
  int2*   btab = (int2*)(ws + 66176);
  int*    nblk = (int*)(ws + 70656);
  bf16*   xb   = (bf16*)(ws + 131072);
  bf16*   d0   = (bf16*)(ws + 131072);
  bf16*   encb = (bf16*)(ws + 131072 + 33554432);
  char*   base = ws + 131072 + 2 * 33554432;
  bf16*   Wb   = (bf16*)(base);
  bf16*   Ubf  = (bf16*)(base + 2097152);
  bf16*   Vb2  = (bf16*)(base + 2 * 2097152);
  int*    lists= (int*)(base + 3 * 2097152);
  float*  wl   = (float*)(base + 4 * 2097152);
  int*    pk   = (int*)(base + 5 * 2097152);
  float2* wpr  = (float2*)(base + 5 * 2097152 + 131072);
  bf16*   d1   = (bf16*)(base + 5 * 2097152 + 131072 + 131072 + 131072);

  hipMemsetAsync(ws, 0, 66048, stream);

  k_cast<<<1024, 256, 0, stream>>>(We, Wb, 1048576 / 4);
  k_cast<<<1024, 256, 0, stream>>>(U, Ubf, 1048576 / 4);
  k_castv<<<512, 256, 0, stream>>>(V, Vb2);

  dim3 gg(4, 16, 8);
  k_gmat<<<gg, 256, 0, stream>>>(Wg, We, Gt2);
  k_bgate<<<16, 256, 0, stream>>>(Wg, be, bg);

  k_gatecast<<<2048, 256, 0, stream>>>(x, Gt2, bg, gam, xb, pk, wpr);
  k_scatter<<<64, 256, 0, stream>>>(pk, wpr, cnt, lists, wl);
  k_btab<<<1, 64, 0, stream>>>(cnt, btab, nblk);

  k_encgemm<<<256, 512, 0, stream>>>(xb, Wb, be, encb);

  k_expert<<<544, 256, 0, stream>>>(encb, Ubf, Vb2, cnt, lists, wl, btab, nblk, d0, d1);
  k_final<<<8192, 256, 0, stream>>>(out, encb, d0, d1);
}